// Round 11
// baseline (322.639 us; speedup 1.0000x reference)
//
#include <hip/hip_runtime.h>
#include <hip/hip_fp16.h>
#include <math.h>

#define NROWS 8192
#define DDIM 384
#define HDIM 256
#define CDIM 6
#define LN_EPS 1e-5f

typedef short bf16x8 __attribute__((ext_vector_type(8)));
typedef float f32x4 __attribute__((ext_vector_type(4)));
typedef unsigned short u16x8 __attribute__((ext_vector_type(8)));
typedef _Float16 f16x8 __attribute__((ext_vector_type(8)));
typedef _Float16 f16x4 __attribute__((ext_vector_type(4)));
typedef _Float16 f16x2 __attribute__((ext_vector_type(2)));

__device__ __forceinline__ bool dj_better(float d1, int j1, float d2, int j2) {
    return (d1 < d2) || (d1 == d2 && j1 < j2);
}

__device__ __forceinline__ unsigned int umin_(unsigned int a, unsigned int b) { return a < b ? a : b; }
__device__ __forceinline__ unsigned int umax_(unsigned int a, unsigned int b) { return a > b ? a : b; }

// fp16 bit pattern -> monotonic u16 (unsigned order == float order)
__device__ __forceinline__ unsigned short map16b(unsigned short b) {
    return (unsigned short)(b ^ (unsigned short)((((short)b) >> 15) | 0x8000));
}

__device__ __forceinline__ unsigned short f16bits(float v) {
    union { _Float16 f; unsigned short u; } c;
    c.f = (_Float16)v;
    return c.u;
}

__device__ __forceinline__ unsigned short rne_bf16(float v) {
    unsigned int u = __float_as_uint(v);
    u += 0x7fffu + ((u >> 16) & 1u);
    return (unsigned short)(u >> 16);
}

// branchless unsorted 8-slot top-8 insert (replace current max, recompute max)
__device__ __forceinline__ void ins8(
    unsigned int& s0, unsigned int& s1, unsigned int& s2, unsigned int& s3,
    unsigned int& s4, unsigned int& s5, unsigned int& s6, unsigned int& s7,
    unsigned int& m, unsigned int key)
{
    if (key < m) {
        s0 = (s0 == m) ? key : s0;
        s1 = (s1 == m) ? key : s1;
        s2 = (s2 == m) ? key : s2;
        s3 = (s3 == m) ? key : s3;
        s4 = (s4 == m) ? key : s4;
        s5 = (s5 == m) ? key : s5;
        s6 = (s6 == m) ? key : s6;
        s7 = (s7 == m) ? key : s7;
        m = umax_(umax_(umax_(s0, s1), umax_(s2, s3)),
                  umax_(umax_(s4, s5), umax_(s6, s7)));
    }
}

// ---------------- prep: xb = bf16(x), sq[i] = ||x_i||^2, k[i] from tau ----------------
__global__ void __launch_bounds__(256) precompute_kernel(
    const float* __restrict__ x, const float* __restrict__ W_tau,
    const float* __restrict__ b_tau, unsigned short* __restrict__ xb,
    float* __restrict__ sq, int* __restrict__ kk)
{
    int tid = threadIdx.x;
    int wave = tid >> 6, lane = tid & 63;
    int row = blockIdx.x * 4 + wave;
    const float* xr = x + (size_t)row * DDIM;
    unsigned short* xbr = xb + (size_t)row * DDIM;
    float s = 0.f, tp = 0.f;
    #pragma unroll
    for (int q = 0; q < 6; ++q) {
        float v = xr[lane + 64 * q];
        xbr[lane + 64 * q] = rne_bf16(v);
        s = fmaf(v, v, s);
        tp = fmaf(v, W_tau[lane + 64 * q], tp);
    }
    #pragma unroll
    for (int off = 32; off > 0; off >>= 1) {
        s += __shfl_xor(s, off);
        tp += __shfl_xor(tp, off);
    }
    if (lane == 0) {
        sq[row] = s;
        float u = tp + b_tau[0];
        float tau = 1.f / (1.f + expf(-u));
        float kf = rintf(16.f - 12.f * tau);
        int k = (int)kf;
        k = min(16, max(1, k));
        kk[row] = k;
    }
}

// ---------------- both weight transposes (fp32 [K][N] -> bf16 [N][K]) ----------------
__global__ void __launch_bounds__(256) transpose_bf16_kernel(
    const float* __restrict__ Wp, unsigned short* __restrict__ wpT,
    const float* __restrict__ Wr, unsigned short* __restrict__ wrT)
{
    int i = blockIdx.x * 256 + threadIdx.x;
    if (i < DDIM * HDIM) {
        int k = i / HDIM, n = i % HDIM;
        wpT[(size_t)n * DDIM + k] = rne_bf16(Wp[i]);
    } else {
        int j = i - DDIM * HDIM;
        if (j < HDIM * HDIM) {
            int k = j / HDIM, n = j % HDIM;
            wrT[(size_t)n * HDIM + k] = rne_bf16(Wr[j]);
        }
    }
}

// ---------------- MFMA bf16 GEMM: out = relu(A[M,K]@W + bias), W given as WT[n][k] ----------------
__global__ void __launch_bounds__(256) mfma_gemm_bias_relu_kernel(
    const unsigned short* __restrict__ A, const unsigned short* __restrict__ WT,
    const float* __restrict__ bias, float* __restrict__ out, int K)
{
    __shared__ unsigned short Abuf[128 * 32];
    __shared__ unsigned short Bbuf[128 * 32];

    const int tid = threadIdx.x;
    const int wave = tid >> 6;
    const int rowbase = blockIdx.x * 128;
    const int nbase = blockIdx.y * 128;
    const int lane = tid & 63;
    const int wr = (wave >> 1) * 64;
    const int wc = (wave & 1) * 64;
    const int m16 = lane & 15;
    const int kq = lane >> 4;

    const int er0 = tid >> 2;
    const int er1 = 64 + (tid >> 2);
    const int eko = tid & 3;

    f32x4 acc[4][4];
    #pragma unroll
    for (int a = 0; a < 4; ++a)
        #pragma unroll
        for (int b = 0; b < 4; ++b)
            acc[a][b] = (f32x4){0.f, 0.f, 0.f, 0.f};

    for (int kb = 0; kb < K / 32; ++kb) {
        const int k0 = kb * 32;
        __syncthreads();
        __builtin_amdgcn_global_load_lds(
            (const __attribute__((address_space(1))) void*)(A + (size_t)(rowbase + er0) * K + k0 + eko * 8),
            (__attribute__((address_space(3))) void*)((char*)Abuf + (wave * 64) * 16), 16, 0, 0);
        __builtin_amdgcn_global_load_lds(
            (const __attribute__((address_space(1))) void*)(A + (size_t)(rowbase + er1) * K + k0 + eko * 8),
            (__attribute__((address_space(3))) void*)((char*)Abuf + (256 + wave * 64) * 16), 16, 0, 0);
        __builtin_amdgcn_global_load_lds(
            (const __attribute__((address_space(1))) void*)(WT + (size_t)(nbase + er0) * K + k0 + eko * 8),
            (__attribute__((address_space(3))) void*)((char*)Bbuf + (wave * 64) * 16), 16, 0, 0);
        __builtin_amdgcn_global_load_lds(
            (const __attribute__((address_space(1))) void*)(WT + (size_t)(nbase + er1) * K + k0 + eko * 8),
            (__attribute__((address_space(3))) void*)((char*)Bbuf + (256 + wave * 64) * 16), 16, 0, 0);
        __syncthreads();

        bf16x8 af[4], bfr[4];
        #pragma unroll
        for (int s = 0; s < 4; ++s) {
            af[s]  = *(const bf16x8*)&Abuf[(wr + s * 16 + m16) * 32 + kq * 8];
            bfr[s] = *(const bf16x8*)&Bbuf[(wc + s * 16 + m16) * 32 + kq * 8];
        }
        #pragma unroll
        for (int si = 0; si < 4; ++si)
            #pragma unroll
            for (int sj = 0; sj < 4; ++sj)
                acc[si][sj] = __builtin_amdgcn_mfma_f32_16x16x32_bf16(
                    af[si], bfr[sj], acc[si][sj], 0, 0, 0);
    }

    #pragma unroll
    for (int sj = 0; sj < 4; ++sj) {
        int c = nbase + wc + sj * 16 + m16;
        float bc = bias[c];
        #pragma unroll
        for (int si = 0; si < 4; ++si) {
            int r = rowbase + wr + si * 16 + kq * 4;
            #pragma unroll
            for (int v = 0; v < 4; ++v)
                out[(size_t)(r + v) * HDIM + c] = fmaxf(acc[si][sj][v] + bc, 0.f);
        }
    }
}

// ---------------- MFMA bf16 Gram GEMM + fused per-tile top-8 screening (v3) ----------------
// Lower-triangle blocks (bi>=bj). Dt holds fp16(-2*dot) for 64 tile-rows per
// round; 4 threads/row scan 32 cols each (top-8), partner shfl-merge -> exact
// top-8 per 64-col half. keys[row][tile][16].
__global__ void __launch_bounds__(256) dist_topk_kernel(
    const unsigned short* __restrict__ xb, const float* __restrict__ sq,
    unsigned int* __restrict__ keys)
{
    __shared__ unsigned short Abuf[128 * 32];                 // 8 KB
    __shared__ unsigned short Bbuf[128 * 32];                 // 8 KB
    __shared__ __align__(16) unsigned short Dt[64 * 136];     // 17.4 KB
    __shared__ unsigned short sqc16[128];
    __shared__ unsigned short sqr16[128];

    int t = blockIdx.x;
    int bi = (int)((sqrtf(8.f * (float)t + 1.f) - 1.f) * 0.5f);
    while ((bi + 1) * (bi + 2) / 2 <= t) ++bi;
    while (bi * (bi + 1) / 2 > t) --bi;
    int bj = t - bi * (bi + 1) / 2;

    const int tid = threadIdx.x;
    const int wave = tid >> 6;
    const int lane = tid & 63;
    const int rowbase = bi * 128;
    const int colbase = bj * 128;
    const int wr = (wave >> 1) * 64;
    const int wc = (wave & 1) * 64;
    const int m16 = lane & 15;
    const int kq = lane >> 4;

    const int er0 = tid >> 2;
    const int er1 = 64 + (tid >> 2);
    const int eko = tid & 3;

    f32x4 acc[4][4];
    #pragma unroll
    for (int a = 0; a < 4; ++a)
        #pragma unroll
        for (int b = 0; b < 4; ++b)
            acc[a][b] = (f32x4){0.f, 0.f, 0.f, 0.f};

    for (int kb = 0; kb < DDIM / 32; ++kb) {
        const int k0 = kb * 32;
        __syncthreads();
        __builtin_amdgcn_global_load_lds(
            (const __attribute__((address_space(1))) void*)(xb + (size_t)(rowbase + er0) * DDIM + k0 + eko * 8),
            (__attribute__((address_space(3))) void*)((char*)Abuf + (wave * 64) * 16), 16, 0, 0);
        __builtin_amdgcn_global_load_lds(
            (const __attribute__((address_space(1))) void*)(xb + (size_t)(rowbase + er1) * DDIM + k0 + eko * 8),
            (__attribute__((address_space(3))) void*)((char*)Abuf + (256 + wave * 64) * 16), 16, 0, 0);
        __builtin_amdgcn_global_load_lds(
            (const __attribute__((address_space(1))) void*)(xb + (size_t)(colbase + er0) * DDIM + k0 + eko * 8),
            (__attribute__((address_space(3))) void*)((char*)Bbuf + (wave * 64) * 16), 16, 0, 0);
        __builtin_amdgcn_global_load_lds(
            (const __attribute__((address_space(1))) void*)(xb + (size_t)(colbase + er1) * DDIM + k0 + eko * 8),
            (__attribute__((address_space(3))) void*)((char*)Bbuf + (256 + wave * 64) * 16), 16, 0, 0);
        __syncthreads();

        bf16x8 af[4], bfr[4];
        #pragma unroll
        for (int s = 0; s < 4; ++s) {
            af[s]  = *(const bf16x8*)&Abuf[(wr + s * 16 + m16) * 32 + kq * 8];
            bfr[s] = *(const bf16x8*)&Bbuf[(wc + s * 16 + m16) * 32 + kq * 8];
        }
        #pragma unroll
        for (int si = 0; si < 4; ++si)
            #pragma unroll
            for (int sj = 0; sj < 4; ++sj)
                acc[si][sj] = __builtin_amdgcn_mfma_f32_16x16x32_bf16(
                    af[si], bfr[sj], acc[si][sj], 0, 0, 0);
    }

    // stage sq as fp16 (visible after first epilogue barrier)
    if (tid < 128) {
        sqc16[tid] = f16bits(sq[colbase + tid]);
        sqr16[tid] = f16bits(sq[rowbase + tid]);
    }

    const int sr = tid >> 2;          // scan row within round (0..63)
    const int qseg = tid & 3;         // 32-col quarter
    const int seg = (tid >> 1) & 1;   // 64-col half (pairs {q0,q1}->0, {q2,q3}->1)

    // ==== pass 1: rows of bi-block (two 64-row rounds) ====
    #pragma unroll
    for (int h = 0; h < 2; ++h) {
        __syncthreads();
        if ((wave >> 1) == h) {
            #pragma unroll
            for (int si = 0; si < 4; ++si)
                #pragma unroll
                for (int sj = 0; sj < 4; ++sj) {
                    int rloc = si * 16 + kq * 4;
                    int c = wc + sj * 16 + m16;
                    #pragma unroll
                    for (int v = 0; v < 4; ++v)
                        Dt[(rloc + v) * 136 + c] = f16bits(-2.0f * acc[si][sj][v]);
                }
        }
        __syncthreads();

        unsigned int s0 = 0xFFFFFFFFu, s1 = 0xFFFFFFFEu, s2 = 0xFFFFFFFDu, s3 = 0xFFFFFFFCu;
        unsigned int s4 = 0xFFFFFFFBu, s5 = 0xFFFFFFFAu, s6 = 0xFFFFFFF9u, s7 = 0xFFFFFFF8u;
        unsigned int m = 0xFFFFFFFFu;
        const unsigned short* rowp = &Dt[sr * 136 + qseg * 32];
        const unsigned short* sqp = &sqc16[qseg * 32];
        #pragma unroll
        for (int i = 0; i < 4; ++i) {
            union { u16x8 u; f16x8 f; } cu, su;
            cu.u = *(const u16x8*)(rowp + i * 8);
            su.u = *(const u16x8*)(sqp + i * 8);
            union { f16x8 f; unsigned short e[8]; } d;
            d.f = cu.f + su.f;                      // v_pk_add_f16
            f16x4 m4 = __builtin_elementwise_min(
                __builtin_shufflevector(d.f, d.f, 0, 1, 2, 3),
                __builtin_shufflevector(d.f, d.f, 4, 5, 6, 7));
            f16x2 m2 = __builtin_elementwise_min(
                __builtin_shufflevector(m4, m4, 0, 1),
                __builtin_shufflevector(m4, m4, 2, 3));
            _Float16 gm = m2[0] < m2[1] ? m2[0] : m2[1];
            union { _Float16 f; unsigned short u; } gb; gb.f = gm;
            if (((unsigned int)map16b(gb.u) << 13) <= m) {
                int cb = colbase + qseg * 32 + i * 8;
                #pragma unroll
                for (int e = 0; e < 8; ++e)
                    ins8(s0, s1, s2, s3, s4, s5, s6, s7, m,
                         ((unsigned int)map16b(d.e[e]) << 13) | (unsigned int)(cb + e));
            }
        }
        // partner merge (tid^1): exact top-8 of the 64-col half
        {
            unsigned int o[8];
            o[0] = (unsigned int)__shfl_xor((int)s0, 1);
            o[1] = (unsigned int)__shfl_xor((int)s1, 1);
            o[2] = (unsigned int)__shfl_xor((int)s2, 1);
            o[3] = (unsigned int)__shfl_xor((int)s3, 1);
            o[4] = (unsigned int)__shfl_xor((int)s4, 1);
            o[5] = (unsigned int)__shfl_xor((int)s5, 1);
            o[6] = (unsigned int)__shfl_xor((int)s6, 1);
            o[7] = (unsigned int)__shfl_xor((int)s7, 1);
            #pragma unroll
            for (int e = 0; e < 8; ++e)
                ins8(s0, s1, s2, s3, s4, s5, s6, s7, m, o[e]);
        }
        if ((tid & 1) == 0) {
            size_t kb = (size_t)(rowbase + h * 64 + sr) * 1024 + (size_t)bj * 16 + seg * 8;
            uint4 o0; o0.x = s0; o0.y = s1; o0.z = s2; o0.w = s3;
            uint4 o1; o1.x = s4; o1.y = s5; o1.z = s6; o1.w = s7;
            *(uint4*)&keys[kb] = o0;
            *(uint4*)&keys[kb + 4] = o1;
        }
    }

    // ==== pass 2: rows of bj-block via transposed tile (off-diagonal only) ====
    if (bi != bj) {
        #pragma unroll
        for (int h = 0; h < 2; ++h) {
            __syncthreads();
            if ((wave & 1) == h) {
                #pragma unroll
                for (int si = 0; si < 4; ++si)
                    #pragma unroll
                    for (int sj = 0; sj < 4; ++sj) {
                        int cloc = sj * 16 + m16;           // 0..63
                        int rr = wr + si * 16 + kq * 4;     // 0..127
                        unsigned short h4[4];
                        #pragma unroll
                        for (int v = 0; v < 4; ++v)
                            h4[v] = f16bits(-2.0f * acc[si][sj][v]);
                        *(unsigned long long*)&Dt[cloc * 136 + rr] = *(unsigned long long*)h4;
                    }
            }
            __syncthreads();

            unsigned int s0 = 0xFFFFFFFFu, s1 = 0xFFFFFFFEu, s2 = 0xFFFFFFFDu, s3 = 0xFFFFFFFCu;
            unsigned int s4 = 0xFFFFFFFBu, s5 = 0xFFFFFFFAu, s6 = 0xFFFFFFF9u, s7 = 0xFFFFFFF8u;
            unsigned int m = 0xFFFFFFFFu;
            const unsigned short* rowp = &Dt[sr * 136 + qseg * 32];
            const unsigned short* sqp = &sqr16[qseg * 32];
            #pragma unroll
            for (int i = 0; i < 4; ++i) {
                union { u16x8 u; f16x8 f; } cu, su;
                cu.u = *(const u16x8*)(rowp + i * 8);
                su.u = *(const u16x8*)(sqp + i * 8);
                union { f16x8 f; unsigned short e[8]; } d;
                d.f = cu.f + su.f;
                f16x4 m4 = __builtin_elementwise_min(
                    __builtin_shufflevector(d.f, d.f, 0, 1, 2, 3),
                    __builtin_shufflevector(d.f, d.f, 4, 5, 6, 7));
                f16x2 m2 = __builtin_elementwise_min(
                    __builtin_shufflevector(m4, m4, 0, 1),
                    __builtin_shufflevector(m4, m4, 2, 3));
                _Float16 gm = m2[0] < m2[1] ? m2[0] : m2[1];
                union { _Float16 f; unsigned short u; } gb; gb.f = gm;
                if (((unsigned int)map16b(gb.u) << 13) <= m) {
                    int cb = rowbase + qseg * 32 + i * 8;
                    #pragma unroll
                    for (int e = 0; e < 8; ++e)
                        ins8(s0, s1, s2, s3, s4, s5, s6, s7, m,
                             ((unsigned int)map16b(d.e[e]) << 13) | (unsigned int)(cb + e));
                }
            }
            {
                unsigned int o[8];
                o[0] = (unsigned int)__shfl_xor((int)s0, 1);
                o[1] = (unsigned int)__shfl_xor((int)s1, 1);
                o[2] = (unsigned int)__shfl_xor((int)s2, 1);
                o[3] = (unsigned int)__shfl_xor((int)s3, 1);
                o[4] = (unsigned int)__shfl_xor((int)s4, 1);
                o[5] = (unsigned int)__shfl_xor((int)s5, 1);
                o[6] = (unsigned int)__shfl_xor((int)s6, 1);
                o[7] = (unsigned int)__shfl_xor((int)s7, 1);
                #pragma unroll
                for (int e = 0; e < 8; ++e)
                    ins8(s0, s1, s2, s3, s4, s5, s6, s7, m, o[e]);
            }
            if ((tid & 1) == 0) {
                size_t kb = (size_t)(colbase + h * 64 + sr) * 1024 + (size_t)bi * 16 + seg * 8;
                uint4 o0; o0.x = s0; o0.y = s1; o0.z = s2; o0.w = s3;
                uint4 o1; o1.x = s4; o1.y = s5; o1.z = s6; o1.w = s7;
                *(uint4*)&keys[kb] = o0;
                *(uint4*)&keys[kb + 4] = o1;
            }
        }
    }
}

// ---------------- merge per-tile keys -> top-32 candidates (1 wave / row) ----------------
__global__ void __launch_bounds__(256) select_merge_kernel(
    const unsigned int* __restrict__ keys, int* __restrict__ cand)
{
    const int row = blockIdx.x * 4 + (threadIdx.x >> 6);
    const int lane = threadIdx.x & 63;
    const uint4* kp = (const uint4*)(keys + (size_t)row * 1024 + lane * 16);

    unsigned int s0 = 0xFFFFFFFFu, s1 = 0xFFFFFFFEu, s2 = 0xFFFFFFFDu, s3 = 0xFFFFFFFCu;
    unsigned int s4 = 0xFFFFFFFBu, s5 = 0xFFFFFFFAu, s6 = 0xFFFFFFF9u, s7 = 0xFFFFFFF8u;
    unsigned int m = 0xFFFFFFFFu;

    #pragma unroll
    for (int q = 0; q < 4; ++q) {
        uint4 v = kp[q];
        unsigned int gmin = umin_(umin_(v.x, v.y), umin_(v.z, v.w));
        if (gmin < m) {
            ins8(s0, s1, s2, s3, s4, s5, s6, s7, m, v.x);
            ins8(s0, s1, s2, s3, s4, s5, s6, s7, m, v.y);
            ins8(s0, s1, s2, s3, s4, s5, s6, s7, m, v.z);
            ins8(s0, s1, s2, s3, s4, s5, s6, s7, m, v.w);
        }
    }

    unsigned int lmin = umin_(umin_(umin_(s0, s1), umin_(s2, s3)),
                              umin_(umin_(s4, s5), umin_(s6, s7)));
    unsigned int myout = 0;
    for (int t = 0; t < 32; ++t) {
        unsigned int w = lmin;
        #pragma unroll
        for (int off = 32; off > 0; off >>= 1)
            w = umin_(w, (unsigned int)__shfl_xor((int)w, off));
        if (lane == t) myout = w;
        if (lmin == w) {
            s0 = (s0 == w) ? 0xFFFFFFFFu : s0;
            s1 = (s1 == w) ? 0xFFFFFFFFu : s1;
            s2 = (s2 == w) ? 0xFFFFFFFFu : s2;
            s3 = (s3 == w) ? 0xFFFFFFFFu : s3;
            s4 = (s4 == w) ? 0xFFFFFFFFu : s4;
            s5 = (s5 == w) ? 0xFFFFFFFFu : s5;
            s6 = (s6 == w) ? 0xFFFFFFFFu : s6;
            s7 = (s7 == w) ? 0xFFFFFFFFu : s7;
            lmin = umin_(umin_(umin_(s0, s1), umin_(s2, s3)),
                         umin_(umin_(s4, s5), umin_(s6, s7)));
        }
    }
    if (lane < 32)
        cand[(size_t)row * 32 + lane] = (int)(myout & 8191u);
}

// ---------------- exact fp32 rescore of 32 candidates -> final sorted top-16 ----------------
__global__ void __launch_bounds__(256) rescore_kernel(
    const float* __restrict__ x, const float* __restrict__ sq,
    const int* __restrict__ cand, int* __restrict__ idxOut)
{
    int row = blockIdx.x * 4 + (threadIdx.x >> 6);
    int lane = threadIdx.x & 63;
    float xr[6];
    #pragma unroll
    for (int q = 0; q < 6; ++q) xr[q] = x[(size_t)row * DDIM + lane + 64 * q];
    int myj = cand[(size_t)row * 32 + (lane & 31)];
    float sqrow = sq[row];
    float myd = 0.f;
    for (int c = 0; c < 32; ++c) {
        int j = __shfl(myj, c);
        const float* xc = x + (size_t)j * DDIM;
        float p = 0.f;
        #pragma unroll
        for (int q = 0; q < 6; ++q) p = fmaf(xr[q], xc[lane + 64 * q], p);
        #pragma unroll
        for (int off = 32; off > 0; off >>= 1) p += __shfl_xor(p, off);
        float d = sqrow + sq[j] - 2.f * p;
        if (lane == c) myd = d;
    }
    int rank = 0;
    for (int t = 0; t < 32; ++t) {
        float dt = __shfl(myd, t); int jt = __shfl(myj, t);
        if (dj_better(dt, jt, myd, myj)) ++rank;
    }
    if (lane < 32 && rank < 16) idxOut[(size_t)row * 16 + rank] = myj;
}

// ---------------- gather-mean -> bf16 agg ----------------
__global__ void __launch_bounds__(256) aggregate_kernel(
    const float* __restrict__ h, const int* __restrict__ idx, const int* __restrict__ kk,
    unsigned short* __restrict__ aggb)
{
    int row = blockIdx.x, tid = threadIdx.x;
    __shared__ int sidx[16];
    __shared__ int sk;
    if (tid < 16) sidx[tid] = idx[(size_t)row * 16 + tid];
    if (tid == 0) sk = kk[row];
    __syncthreads();
    int k = sk;
    float acc = 0.f;
    for (int t = 0; t < k; ++t) acc += h[(size_t)sidx[t] * HDIM + tid];
    aggb[(size_t)row * HDIM + tid] = rne_bf16(acc / (float)k);
}

// ---------------- LayerNorm(h + r) * g + b, then @ W_fc + b_fc ----------------
__global__ void __launch_bounds__(256) ln_fc_kernel(
    const float* __restrict__ h, const float* __restrict__ r,
    const float* __restrict__ g, const float* __restrict__ bb,
    const float* __restrict__ W_fc, const float* __restrict__ b_fc,
    float* __restrict__ out)
{
    int row = blockIdx.x, tid = threadIdx.x;
    int wave = tid >> 6, lane = tid & 63;
    float z = h[(size_t)row * HDIM + tid] + r[(size_t)row * HDIM + tid];
    float s = z, s2 = z * z;
    #pragma unroll
    for (int off = 32; off > 0; off >>= 1) { s += __shfl_xor(s, off); s2 += __shfl_xor(s2, off); }
    __shared__ float red[8];
    __shared__ float smv[2];
    if (lane == 0) { red[wave] = s; red[4 + wave] = s2; }
    __syncthreads();
    if (tid == 0) {
        float ts = red[0] + red[1] + red[2] + red[3];
        float t2 = red[4] + red[5] + red[6] + red[7];
        float mu = ts / 256.f;
        float var = t2 / 256.f - mu * mu;
        smv[0] = mu; smv[1] = rsqrtf(var + LN_EPS);
    }
    __syncthreads();
    float zn = (z - smv[0]) * smv[1];
    float val = zn * g[tid] + bb[tid];
    float p[6];
    #pragma unroll
    for (int c = 0; c < 6; ++c) p[c] = val * W_fc[tid * 6 + c];
    #pragma unroll
    for (int c = 0; c < 6; ++c)
        #pragma unroll
        for (int off = 32; off > 0; off >>= 1) p[c] += __shfl_xor(p[c], off);
    __shared__ float pr[4][6];
    if (lane == 0) {
        #pragma unroll
        for (int c = 0; c < 6; ++c) pr[wave][c] = p[c];
    }
    __syncthreads();
    if (tid < 6)
        out[(size_t)row * CDIM + tid] = pr[0][tid] + pr[1][tid] + pr[2][tid] + pr[3][tid] + b_fc[tid];
}

extern "C" void kernel_launch(void* const* d_in, const int* in_sizes, int n_in,
                              void* d_out, int out_size, void* d_ws, size_t ws_size,
                              hipStream_t stream) {
    const float* x      = (const float*)d_in[0];
    const float* W_proj = (const float*)d_in[1];
    const float* b_proj = (const float*)d_in[2];
    const float* W_tau  = (const float*)d_in[3];
    const float* b_tau  = (const float*)d_in[4];
    const float* W_res  = (const float*)d_in[5];
    const float* b_res  = (const float*)d_in[6];
    const float* ln_g   = (const float*)d_in[7];
    const float* ln_b   = (const float*)d_in[8];
    const float* W_fc   = (const float*)d_in[9];
    const float* b_fc   = (const float*)d_in[10];
    float* out = (float*)d_out;

    char* ws = (char*)d_ws;
    float* sq   = (float*)ws;                        ws += (size_t)NROWS * 4;
    int*   kk   = (int*)ws;                          ws += (size_t)NROWS * 4;
    float* h    = (float*)ws;                        ws += (size_t)NROWS * HDIM * 4;
    float* r    = (float*)ws;                        ws += (size_t)NROWS * HDIM * 4;
    int*   idx  = (int*)ws;                          ws += (size_t)NROWS * 16 * 4;
    int*   cand = (int*)ws;                          ws += (size_t)NROWS * 32 * 4;
    unsigned short* xb   = (unsigned short*)ws;      ws += (size_t)NROWS * DDIM * 2;
    unsigned short* aggb = (unsigned short*)ws;      ws += (size_t)NROWS * HDIM * 2;
    unsigned short* wpT  = (unsigned short*)ws;      ws += (size_t)DDIM * HDIM * 2;
    unsigned short* wrT  = (unsigned short*)ws;      ws += (size_t)HDIM * HDIM * 2;
    ws = (char*)(((size_t)ws + 255) & ~(size_t)255);
    unsigned int* keys = (unsigned int*)ws;          ws += (size_t)NROWS * 1024 * 4;   // 32 MB

    precompute_kernel<<<NROWS / 4, 256, 0, stream>>>(x, W_tau, b_tau, xb, sq, kk);
    transpose_bf16_kernel<<<(DDIM * HDIM + HDIM * HDIM + 255) / 256, 256, 0, stream>>>(
        W_proj, wpT, W_res, wrT);
    mfma_gemm_bias_relu_kernel<<<dim3(NROWS / 128, HDIM / 128), 256, 0, stream>>>(
        xb, wpT, b_proj, h, DDIM);
    dist_topk_kernel<<<(NROWS/128) * (NROWS/128 + 1) / 2, 256, 0, stream>>>(xb, sq, keys);
    select_merge_kernel<<<NROWS / 4, 256, 0, stream>>>(keys, cand);
    rescore_kernel<<<NROWS / 4, 256, 0, stream>>>(x, sq, cand, idx);
    aggregate_kernel<<<NROWS, 256, 0, stream>>>(h, idx, kk, aggb);
    mfma_gemm_bias_relu_kernel<<<dim3(NROWS / 128, HDIM / 128), 256, 0, stream>>>(
        aggb, wrT, b_res, r, HDIM);
    ln_fc_kernel<<<NROWS, 256, 0, stream>>>(h, r, ln_g, ln_b, W_fc, b_fc, out);
}

// Round 12
// 286.323 us; speedup vs baseline: 1.1268x; 1.1268x over previous
//
#include <hip/hip_runtime.h>
#include <hip/hip_fp16.h>
#include <math.h>

#define NROWS 8192
#define DDIM 384
#define HDIM 256
#define CDIM 6
#define LN_EPS 1e-5f
#define DSTR 138   // Dt row stride in halves: 69 dwords, odd -> conflict-free scan

typedef short bf16x8 __attribute__((ext_vector_type(8)));
typedef float f32x4 __attribute__((ext_vector_type(4)));
typedef unsigned short u16x8 __attribute__((ext_vector_type(8)));
typedef unsigned short u16x4 __attribute__((ext_vector_type(4)));
typedef unsigned short u16x2 __attribute__((ext_vector_type(2)));

__device__ __forceinline__ bool dj_better(float d1, int j1, float d2, int j2) {
    return (d1 < d2) || (d1 == d2 && j1 < j2);
}

__device__ __forceinline__ unsigned int umin_(unsigned int a, unsigned int b) { return a < b ? a : b; }
__device__ __forceinline__ unsigned int umax_(unsigned int a, unsigned int b) { return a > b ? a : b; }

// fp32 -> fp16 -> monotonic u16 (unsigned order == float order)
__device__ __forceinline__ unsigned short map16f(float v) {
    union { _Float16 f; unsigned short u; } c;
    c.f = (_Float16)v;
    unsigned short b = c.u;
    return (unsigned short)(b ^ (unsigned short)((((short)b) >> 15) | 0x8000));
}

__device__ __forceinline__ unsigned short rne_bf16(float v) {
    unsigned int u = __float_as_uint(v);
    u += 0x7fffu + ((u >> 16) & 1u);
    return (unsigned short)(u >> 16);
}

// branchless unsorted 8-slot top-8 insert (replace current max, recompute max)
__device__ __forceinline__ void ins8(
    unsigned int& s0, unsigned int& s1, unsigned int& s2, unsigned int& s3,
    unsigned int& s4, unsigned int& s5, unsigned int& s6, unsigned int& s7,
    unsigned int& m, unsigned int key)
{
    if (key < m) {
        s0 = (s0 == m) ? key : s0;
        s1 = (s1 == m) ? key : s1;
        s2 = (s2 == m) ? key : s2;
        s3 = (s3 == m) ? key : s3;
        s4 = (s4 == m) ? key : s4;
        s5 = (s5 == m) ? key : s5;
        s6 = (s6 == m) ? key : s6;
        s7 = (s7 == m) ? key : s7;
        m = umax_(umax_(umax_(s0, s1), umax_(s2, s3)),
                  umax_(umax_(s4, s5), umax_(s6, s7)));
    }
}

// ---------------- prep: xb = bf16(x), sq[i] = ||x_i||^2, k[i] from tau ----------------
__global__ void __launch_bounds__(256) precompute_kernel(
    const float* __restrict__ x, const float* __restrict__ W_tau,
    const float* __restrict__ b_tau, unsigned short* __restrict__ xb,
    float* __restrict__ sq, int* __restrict__ kk)
{
    int tid = threadIdx.x;
    int wave = tid >> 6, lane = tid & 63;
    int row = blockIdx.x * 4 + wave;
    const float* xr = x + (size_t)row * DDIM;
    unsigned short* xbr = xb + (size_t)row * DDIM;
    float s = 0.f, tp = 0.f;
    #pragma unroll
    for (int q = 0; q < 6; ++q) {
        float v = xr[lane + 64 * q];
        xbr[lane + 64 * q] = rne_bf16(v);
        s = fmaf(v, v, s);
        tp = fmaf(v, W_tau[lane + 64 * q], tp);
    }
    #pragma unroll
    for (int off = 32; off > 0; off >>= 1) {
        s += __shfl_xor(s, off);
        tp += __shfl_xor(tp, off);
    }
    if (lane == 0) {
        sq[row] = s;
        float u = tp + b_tau[0];
        float tau = 1.f / (1.f + expf(-u));
        float kf = rintf(16.f - 12.f * tau);
        int k = (int)kf;
        k = min(16, max(1, k));
        kk[row] = k;
    }
}

// ---------------- both weight transposes (fp32 [K][N] -> bf16 [N][K]) ----------------
__global__ void __launch_bounds__(256) transpose_bf16_kernel(
    const float* __restrict__ Wp, unsigned short* __restrict__ wpT,
    const float* __restrict__ Wr, unsigned short* __restrict__ wrT)
{
    int i = blockIdx.x * 256 + threadIdx.x;
    if (i < DDIM * HDIM) {
        int k = i / HDIM, n = i % HDIM;
        wpT[(size_t)n * DDIM + k] = rne_bf16(Wp[i]);
    } else {
        int j = i - DDIM * HDIM;
        if (j < HDIM * HDIM) {
            int k = j / HDIM, n = j % HDIM;
            wrT[(size_t)n * HDIM + k] = rne_bf16(Wr[j]);
        }
    }
}

// ---------------- MFMA bf16 GEMM: out = relu(A[M,K]@W + bias), W given as WT[n][k] ----------------
__global__ void __launch_bounds__(256) mfma_gemm_bias_relu_kernel(
    const unsigned short* __restrict__ A, const unsigned short* __restrict__ WT,
    const float* __restrict__ bias, float* __restrict__ out, int K)
{
    __shared__ unsigned short Abuf[128 * 32];
    __shared__ unsigned short Bbuf[128 * 32];

    const int tid = threadIdx.x;
    const int wave = tid >> 6;
    const int rowbase = blockIdx.x * 128;
    const int nbase = blockIdx.y * 128;
    const int lane = tid & 63;
    const int wr = (wave >> 1) * 64;
    const int wc = (wave & 1) * 64;
    const int m16 = lane & 15;
    const int kq = lane >> 4;

    const int er0 = tid >> 2;
    const int er1 = 64 + (tid >> 2);
    const int eko = tid & 3;

    f32x4 acc[4][4];
    #pragma unroll
    for (int a = 0; a < 4; ++a)
        #pragma unroll
        for (int b = 0; b < 4; ++b)
            acc[a][b] = (f32x4){0.f, 0.f, 0.f, 0.f};

    for (int kb = 0; kb < K / 32; ++kb) {
        const int k0 = kb * 32;
        __syncthreads();
        __builtin_amdgcn_global_load_lds(
            (const __attribute__((address_space(1))) void*)(A + (size_t)(rowbase + er0) * K + k0 + eko * 8),
            (__attribute__((address_space(3))) void*)((char*)Abuf + (wave * 64) * 16), 16, 0, 0);
        __builtin_amdgcn_global_load_lds(
            (const __attribute__((address_space(1))) void*)(A + (size_t)(rowbase + er1) * K + k0 + eko * 8),
            (__attribute__((address_space(3))) void*)((char*)Abuf + (256 + wave * 64) * 16), 16, 0, 0);
        __builtin_amdgcn_global_load_lds(
            (const __attribute__((address_space(1))) void*)(WT + (size_t)(nbase + er0) * K + k0 + eko * 8),
            (__attribute__((address_space(3))) void*)((char*)Bbuf + (wave * 64) * 16), 16, 0, 0);
        __builtin_amdgcn_global_load_lds(
            (const __attribute__((address_space(1))) void*)(WT + (size_t)(nbase + er1) * K + k0 + eko * 8),
            (__attribute__((address_space(3))) void*)((char*)Bbuf + (256 + wave * 64) * 16), 16, 0, 0);
        __syncthreads();

        bf16x8 af[4], bfr[4];
        #pragma unroll
        for (int s = 0; s < 4; ++s) {
            af[s]  = *(const bf16x8*)&Abuf[(wr + s * 16 + m16) * 32 + kq * 8];
            bfr[s] = *(const bf16x8*)&Bbuf[(wc + s * 16 + m16) * 32 + kq * 8];
        }
        #pragma unroll
        for (int si = 0; si < 4; ++si)
            #pragma unroll
            for (int sj = 0; sj < 4; ++sj)
                acc[si][sj] = __builtin_amdgcn_mfma_f32_16x16x32_bf16(
                    af[si], bfr[sj], acc[si][sj], 0, 0, 0);
    }

    #pragma unroll
    for (int sj = 0; sj < 4; ++sj) {
        int c = nbase + wc + sj * 16 + m16;
        float bc = bias[c];
        #pragma unroll
        for (int si = 0; si < 4; ++si) {
            int r = rowbase + wr + si * 16 + kq * 4;
            #pragma unroll
            for (int v = 0; v < 4; ++v)
                out[(size_t)(r + v) * HDIM + c] = fmaxf(acc[si][sj][v] + bc, 0.f);
        }
    }
}

// ---------------- MFMA bf16 Gram GEMM + fused per-tile top-8 screening ----------------
// R9 structure (full 128-row Dt, 2 threads/row scan, 4 epilogue barriers),
// with odd Dt stride (69 dwords) to kill the 8-way ds_read_b128 conflicts.
// keys[row][tile][16], key = mapped_u16(fp16(sq[col]-2dot)) << 13 | col.
__global__ void __launch_bounds__(256) dist_topk_kernel(
    const unsigned short* __restrict__ xb, const float* __restrict__ sq,
    unsigned int* __restrict__ keys)
{
    __shared__ unsigned short Abuf[128 * 32];                 // 8 KB
    __shared__ unsigned short Bbuf[128 * 32];                 // 8 KB
    __shared__ __align__(16) unsigned short Dt[128 * DSTR];   // 34.5 KB

    int t = blockIdx.x;
    int bi = (int)((sqrtf(8.f * (float)t + 1.f) - 1.f) * 0.5f);
    while ((bi + 1) * (bi + 2) / 2 <= t) ++bi;
    while (bi * (bi + 1) / 2 > t) --bi;
    int bj = t - bi * (bi + 1) / 2;

    const int tid = threadIdx.x;
    const int wave = tid >> 6;
    const int lane = tid & 63;
    const int rowbase = bi * 128;
    const int colbase = bj * 128;
    const int wr = (wave >> 1) * 64;
    const int wc = (wave & 1) * 64;
    const int m16 = lane & 15;
    const int kq = lane >> 4;

    const int er0 = tid >> 2;
    const int er1 = 64 + (tid >> 2);
    const int eko = tid & 3;

    f32x4 acc[4][4];
    #pragma unroll
    for (int a = 0; a < 4; ++a)
        #pragma unroll
        for (int b = 0; b < 4; ++b)
            acc[a][b] = (f32x4){0.f, 0.f, 0.f, 0.f};

    for (int kb = 0; kb < DDIM / 32; ++kb) {
        const int k0 = kb * 32;
        __syncthreads();
        __builtin_amdgcn_global_load_lds(
            (const __attribute__((address_space(1))) void*)(xb + (size_t)(rowbase + er0) * DDIM + k0 + eko * 8),
            (__attribute__((address_space(3))) void*)((char*)Abuf + (wave * 64) * 16), 16, 0, 0);
        __builtin_amdgcn_global_load_lds(
            (const __attribute__((address_space(1))) void*)(xb + (size_t)(rowbase + er1) * DDIM + k0 + eko * 8),
            (__attribute__((address_space(3))) void*)((char*)Abuf + (256 + wave * 64) * 16), 16, 0, 0);
        __builtin_amdgcn_global_load_lds(
            (const __attribute__((address_space(1))) void*)(xb + (size_t)(colbase + er0) * DDIM + k0 + eko * 8),
            (__attribute__((address_space(3))) void*)((char*)Bbuf + (wave * 64) * 16), 16, 0, 0);
        __builtin_amdgcn_global_load_lds(
            (const __attribute__((address_space(1))) void*)(xb + (size_t)(colbase + er1) * DDIM + k0 + eko * 8),
            (__attribute__((address_space(3))) void*)((char*)Bbuf + (256 + wave * 64) * 16), 16, 0, 0);
        __syncthreads();

        bf16x8 af[4], bfr[4];
        #pragma unroll
        for (int s = 0; s < 4; ++s) {
            af[s]  = *(const bf16x8*)&Abuf[(wr + s * 16 + m16) * 32 + kq * 8];
            bfr[s] = *(const bf16x8*)&Bbuf[(wc + s * 16 + m16) * 32 + kq * 8];
        }
        #pragma unroll
        for (int si = 0; si < 4; ++si)
            #pragma unroll
            for (int sj = 0; sj < 4; ++sj)
                acc[si][sj] = __builtin_amdgcn_mfma_f32_16x16x32_bf16(
                    af[si], bfr[sj], acc[si][sj], 0, 0, 0);
    }

    const int sr = tid >> 1;          // scan row in tile (0..127)
    const int seg = tid & 1;          // 64-col half

    // ==== pass 1: rows of bi-block ====
    {
        float sqc[4];
        #pragma unroll
        for (int sj = 0; sj < 4; ++sj) sqc[sj] = sq[colbase + wc + sj * 16 + m16];
        #pragma unroll
        for (int si = 0; si < 4; ++si)
            #pragma unroll
            for (int sj = 0; sj < 4; ++sj) {
                int r = wr + si * 16 + kq * 4;
                int c = wc + sj * 16 + m16;
                #pragma unroll
                for (int v = 0; v < 4; ++v)
                    Dt[(r + v) * DSTR + c] = map16f(sqc[sj] - 2.0f * acc[si][sj][v]);
            }
        __syncthreads();

        unsigned int s0 = 0xFFFFFFFFu, s1 = 0xFFFFFFFEu, s2 = 0xFFFFFFFDu, s3 = 0xFFFFFFFCu;
        unsigned int s4 = 0xFFFFFFFBu, s5 = 0xFFFFFFFAu, s6 = 0xFFFFFFF9u, s7 = 0xFFFFFFF8u;
        unsigned int m = 0xFFFFFFFFu;
        const unsigned short* rowp = &Dt[sr * DSTR + seg * 64];
        #pragma unroll
        for (int i = 0; i < 8; ++i) {
            u16x8 ch = *(const u16x8*)(rowp + i * 8);
            u16x4 g4 = __builtin_elementwise_min(
                __builtin_shufflevector(ch, ch, 0, 1, 2, 3),
                __builtin_shufflevector(ch, ch, 4, 5, 6, 7));
            u16x2 g2 = __builtin_elementwise_min(
                __builtin_shufflevector(g4, g4, 0, 1),
                __builtin_shufflevector(g4, g4, 2, 3));
            unsigned int gmin = umin_((unsigned int)g2[0], (unsigned int)g2[1]);
            if ((gmin << 13) < m) {
                int cb = colbase + seg * 64 + i * 8;
                #pragma unroll
                for (int e = 0; e < 8; ++e)
                    ins8(s0, s1, s2, s3, s4, s5, s6, s7, m,
                         ((unsigned int)ch[e] << 13) | (unsigned int)(cb + e));
            }
        }
        size_t kb = (size_t)(rowbase + sr) * 1024 + (size_t)bj * 16 + seg * 8;
        uint4 o0; o0.x = s0; o0.y = s1; o0.z = s2; o0.w = s3;
        uint4 o1; o1.x = s4; o1.y = s5; o1.z = s6; o1.w = s7;
        *(uint4*)&keys[kb] = o0;
        *(uint4*)&keys[kb + 4] = o1;
    }

    // ==== pass 2: rows of bj-block via transposed tile (off-diagonal only) ====
    if (bi != bj) {
        __syncthreads();
        #pragma unroll
        for (int si = 0; si < 4; ++si) {
            float4 sqr4 = *(const float4*)&sq[rowbase + wr + si * 16 + kq * 4];
            float srw[4] = {sqr4.x, sqr4.y, sqr4.z, sqr4.w};
            #pragma unroll
            for (int sj = 0; sj < 4; ++sj) {
                int r = wr + si * 16 + kq * 4;
                int c = wc + sj * 16 + m16;
                unsigned short h4[4];
                #pragma unroll
                for (int v = 0; v < 4; ++v)
                    h4[v] = map16f(srw[v] - 2.0f * acc[si][sj][v]);
                *(unsigned long long*)&Dt[c * DSTR + r] = *(unsigned long long*)h4;
            }
        }
        __syncthreads();

        unsigned int s0 = 0xFFFFFFFFu, s1 = 0xFFFFFFFEu, s2 = 0xFFFFFFFDu, s3 = 0xFFFFFFFCu;
        unsigned int s4 = 0xFFFFFFFBu, s5 = 0xFFFFFFFAu, s6 = 0xFFFFFFF9u, s7 = 0xFFFFFFF8u;
        unsigned int m = 0xFFFFFFFFu;
        const unsigned short* rowp = &Dt[sr * DSTR + seg * 64];
        #pragma unroll
        for (int i = 0; i < 8; ++i) {
            u16x8 ch = *(const u16x8*)(rowp + i * 8);
            u16x4 g4 = __builtin_elementwise_min(
                __builtin_shufflevector(ch, ch, 0, 1, 2, 3),
                __builtin_shufflevector(ch, ch, 4, 5, 6, 7));
            u16x2 g2 = __builtin_elementwise_min(
                __builtin_shufflevector(g4, g4, 0, 1),
                __builtin_shufflevector(g4, g4, 2, 3));
            unsigned int gmin = umin_((unsigned int)g2[0], (unsigned int)g2[1]);
            if ((gmin << 13) < m) {
                int cb = rowbase + seg * 64 + i * 8;
                #pragma unroll
                for (int e = 0; e < 8; ++e)
                    ins8(s0, s1, s2, s3, s4, s5, s6, s7, m,
                         ((unsigned int)ch[e] << 13) | (unsigned int)(cb + e));
            }
        }
        size_t kb = (size_t)(colbase + sr) * 1024 + (size_t)bi * 16 + seg * 8;
        uint4 o0; o0.x = s0; o0.y = s1; o0.z = s2; o0.w = s3;
        uint4 o1; o1.x = s4; o1.y = s5; o1.z = s6; o1.w = s7;
        *(uint4*)&keys[kb] = o0;
        *(uint4*)&keys[kb + 4] = o1;
    }
}

// ---------------- merge per-tile keys -> top-32 candidates (1 wave / row) ----------------
__global__ void __launch_bounds__(256) select_merge_kernel(
    const unsigned int* __restrict__ keys, int* __restrict__ cand)
{
    const int row = blockIdx.x * 4 + (threadIdx.x >> 6);
    const int lane = threadIdx.x & 63;
    const uint4* kp = (const uint4*)(keys + (size_t)row * 1024 + lane * 16);

    unsigned int s0 = 0xFFFFFFFFu, s1 = 0xFFFFFFFEu, s2 = 0xFFFFFFFDu, s3 = 0xFFFFFFFCu;
    unsigned int s4 = 0xFFFFFFFBu, s5 = 0xFFFFFFFAu, s6 = 0xFFFFFFF9u, s7 = 0xFFFFFFF8u;
    unsigned int m = 0xFFFFFFFFu;

    #pragma unroll
    for (int q = 0; q < 4; ++q) {
        uint4 v = kp[q];
        unsigned int gmin = umin_(umin_(v.x, v.y), umin_(v.z, v.w));
        if (gmin < m) {
            ins8(s0, s1, s2, s3, s4, s5, s6, s7, m, v.x);
            ins8(s0, s1, s2, s3, s4, s5, s6, s7, m, v.y);
            ins8(s0, s1, s2, s3, s4, s5, s6, s7, m, v.z);
            ins8(s0, s1, s2, s3, s4, s5, s6, s7, m, v.w);
        }
    }

    unsigned int lmin = umin_(umin_(umin_(s0, s1), umin_(s2, s3)),
                              umin_(umin_(s4, s5), umin_(s6, s7)));
    unsigned int myout = 0;
    for (int t = 0; t < 32; ++t) {
        unsigned int w = lmin;
        #pragma unroll
        for (int off = 32; off > 0; off >>= 1)
            w = umin_(w, (unsigned int)__shfl_xor((int)w, off));
        if (lane == t) myout = w;
        if (lmin == w) {
            s0 = (s0 == w) ? 0xFFFFFFFFu : s0;
            s1 = (s1 == w) ? 0xFFFFFFFFu : s1;
            s2 = (s2 == w) ? 0xFFFFFFFFu : s2;
            s3 = (s3 == w) ? 0xFFFFFFFFu : s3;
            s4 = (s4 == w) ? 0xFFFFFFFFu : s4;
            s5 = (s5 == w) ? 0xFFFFFFFFu : s5;
            s6 = (s6 == w) ? 0xFFFFFFFFu : s6;
            s7 = (s7 == w) ? 0xFFFFFFFFu : s7;
            lmin = umin_(umin_(umin_(s0, s1), umin_(s2, s3)),
                         umin_(umin_(s4, s5), umin_(s6, s7)));
        }
    }
    if (lane < 32)
        cand[(size_t)row * 32 + lane] = (int)(myout & 8191u);
}

// ---------------- exact fp32 rescore of 32 candidates -> final sorted top-16 ----------------
__global__ void __launch_bounds__(256) rescore_kernel(
    const float* __restrict__ x, const float* __restrict__ sq,
    const int* __restrict__ cand, int* __restrict__ idxOut)
{
    int row = blockIdx.x * 4 + (threadIdx.x >> 6);
    int lane = threadIdx.x & 63;
    float xr[6];
    #pragma unroll
    for (int q = 0; q < 6; ++q) xr[q] = x[(size_t)row * DDIM + lane + 64 * q];
    int myj = cand[(size_t)row * 32 + (lane & 31)];
    float sqrow = sq[row];
    float myd = 0.f;
    for (int c = 0; c < 32; ++c) {
        int j = __shfl(myj, c);
        const float* xc = x + (size_t)j * DDIM;
        float p = 0.f;
        #pragma unroll
        for (int q = 0; q < 6; ++q) p = fmaf(xr[q], xc[lane + 64 * q], p);
        #pragma unroll
        for (int off = 32; off > 0; off >>= 1) p += __shfl_xor(p, off);
        float d = sqrow + sq[j] - 2.f * p;
        if (lane == c) myd = d;
    }
    int rank = 0;
    for (int t = 0; t < 32; ++t) {
        float dt = __shfl(myd, t); int jt = __shfl(myj, t);
        if (dj_better(dt, jt, myd, myj)) ++rank;
    }
    if (lane < 32 && rank < 16) idxOut[(size_t)row * 16 + rank] = myj;
}

// ---------------- gather-mean -> bf16 agg ----------------
__global__ void __launch_bounds__(256) aggregate_kernel(
    const float* __restrict__ h, const int* __restrict__ idx, const int* __restrict__ kk,
    unsigned short* __restrict__ aggb)
{
    int row = blockIdx.x, tid = threadIdx.x;
    __shared__ int sidx[16];
    __shared__ int sk;
    if (tid < 16) sidx[tid] = idx[(size_t)row * 16 + tid];
    if (tid == 0) sk = kk[row];
    __syncthreads();
    int k = sk;
    float acc = 0.f;
    for (int t = 0; t < k; ++t) acc += h[(size_t)sidx[t] * HDIM + tid];
    aggb[(size_t)row * HDIM + tid] = rne_bf16(acc / (float)k);
}

// ---------------- LayerNorm(h + r) * g + b, then @ W_fc + b_fc ----------------
__global__ void __launch_bounds__(256) ln_fc_kernel(
    const float* __restrict__ h, const float* __restrict__ r,
    const float* __restrict__ g, const float* __restrict__ bb,
    const float* __restrict__ W_fc, const float* __restrict__ b_fc,
    float* __restrict__ out)
{
    int row = blockIdx.x, tid = threadIdx.x;
    int wave = tid >> 6, lane = tid & 63;
    float z = h[(size_t)row * HDIM + tid] + r[(size_t)row * HDIM + tid];
    float s = z, s2 = z * z;
    #pragma unroll
    for (int off = 32; off > 0; off >>= 1) { s += __shfl_xor(s, off); s2 += __shfl_xor(s2, off); }
    __shared__ float red[8];
    __shared__ float smv[2];
    if (lane == 0) { red[wave] = s; red[4 + wave] = s2; }
    __syncthreads();
    if (tid == 0) {
        float ts = red[0] + red[1] + red[2] + red[3];
        float t2 = red[4] + red[5] + red[6] + red[7];
        float mu = ts / 256.f;
        float var = t2 / 256.f - mu * mu;
        smv[0] = mu; smv[1] = rsqrtf(var + LN_EPS);
    }
    __syncthreads();
    float zn = (z - smv[0]) * smv[1];
    float val = zn * g[tid] + bb[tid];
    float p[6];
    #pragma unroll
    for (int c = 0; c < 6; ++c) p[c] = val * W_fc[tid * 6 + c];
    #pragma unroll
    for (int c = 0; c < 6; ++c)
        #pragma unroll
        for (int off = 32; off > 0; off >>= 1) p[c] += __shfl_xor(p[c], off);
    __shared__ float pr[4][6];
    if (lane == 0) {
        #pragma unroll
        for (int c = 0; c < 6; ++c) pr[wave][c] = p[c];
    }
    __syncthreads();
    if (tid < 6)
        out[(size_t)row * CDIM + tid] = pr[0][tid] + pr[1][tid] + pr[2][tid] + pr[3][tid] + b_fc[tid];
}

extern "C" void kernel_launch(void* const* d_in, const int* in_sizes, int n_in,
                              void* d_out, int out_size, void* d_ws, size_t ws_size,
                              hipStream_t stream) {
    const float* x      = (const float*)d_in[0];
    const float* W_proj = (const float*)d_in[1];
    const float* b_proj = (const float*)d_in[2];
    const float* W_tau  = (const float*)d_in[3];
    const float* b_tau  = (const float*)d_in[4];
    const float* W_res  = (const float*)d_in[5];
    const float* b_res  = (const float*)d_in[6];
    const float* ln_g   = (const float*)d_in[7];
    const float* ln_b   = (const float*)d_in[8];
    const float* W_fc   = (const float*)d_in[9];
    const float* b_fc   = (const float*)d_in[10];
    float* out = (float*)d_out;

    char* ws = (char*)d_ws;
    float* sq   = (float*)ws;                        ws += (size_t)NROWS * 4;
    int*   kk   = (int*)ws;                          ws += (size_t)NROWS * 4;
    float* h    = (float*)ws;                        ws += (size_t)NROWS * HDIM * 4;
    float* r    = (float*)ws;                        ws += (size_t)NROWS * HDIM * 4;
    int*   idx  = (int*)ws;                          ws += (size_t)NROWS * 16 * 4;
    int*   cand = (int*)ws;                          ws += (size_t)NROWS * 32 * 4;
    unsigned short* xb   = (unsigned short*)ws;      ws += (size_t)NROWS * DDIM * 2;
    unsigned short* aggb = (unsigned short*)ws;      ws += (size_t)NROWS * HDIM * 2;
    unsigned short* wpT  = (unsigned short*)ws;      ws += (size_t)DDIM * HDIM * 2;
    unsigned short* wrT  = (unsigned short*)ws;      ws += (size_t)HDIM * HDIM * 2;
    ws = (char*)(((size_t)ws + 255) & ~(size_t)255);
    unsigned int* keys = (unsigned int*)ws;          ws += (size_t)NROWS * 1024 * 4;   // 32 MB

    precompute_kernel<<<NROWS / 4, 256, 0, stream>>>(x, W_tau, b_tau, xb, sq, kk);
    transpose_bf16_kernel<<<(DDIM * HDIM + HDIM * HDIM + 255) / 256, 256, 0, stream>>>(
        W_proj, wpT, W_res, wrT);
    mfma_gemm_bias_relu_kernel<<<dim3(NROWS / 128, HDIM / 128), 256, 0, stream>>>(
        xb, wpT, b_proj, h, DDIM);
    dist_topk_kernel<<<(NROWS/128) * (NROWS/128 + 1) / 2, 256, 0, stream>>>(xb, sq, keys);
    select_merge_kernel<<<NROWS / 4, 256, 0, stream>>>(keys, cand);
    rescore_kernel<<<NROWS / 4, 256, 0, stream>>>(x, sq, cand, idx);
    aggregate_kernel<<<NROWS, 256, 0, stream>>>(h, idx, kk, aggb);
    mfma_gemm_bias_relu_kernel<<<dim3(NROWS / 128, HDIM / 128), 256, 0, stream>>>(
        aggb, wrT, b_res, r, HDIM);
    ln_fc_kernel<<<NROWS, 256, 0, stream>>>(h, r, ln_g, ln_b, W_fc, b_fc, out);
}